// Round 11
// baseline (13197.874 us; speedup 1.0000x reference)
//
#include <hip/hip_runtime.h>
#include <math.h>

#define Dm 1024
#define Bm 8
#define Sm 512

typedef short s16x8 __attribute__((ext_vector_type(8)));
typedef float f32x4 __attribute__((ext_vector_type(4)));
typedef unsigned short u16;
typedef unsigned long long u64;

__device__ __forceinline__ float bf2f(u16 u) {
  union { float f; unsigned v; } x; x.v = (unsigned)u << 16; return x.f;
}
__device__ __forceinline__ u16 f2bf(float f) {
  union { float f; unsigned v; } x; x.f = f;
  unsigned r = x.v + 0x7FFFu + ((x.v >> 16) & 1u);
  return (u16)(r >> 16);
}
__device__ __forceinline__ float sigm(float x) { return 1.f / (1.f + expf(-x)); }

// coherent (agent-scope) access helpers
__device__ __forceinline__ u64 cld64(const void* p) {
  return __hip_atomic_load((const u64*)p, __ATOMIC_RELAXED, __HIP_MEMORY_SCOPE_AGENT);
}
__device__ __forceinline__ float cldf(const void* p) {
  return __hip_atomic_load((const float*)p, __ATOMIC_RELAXED, __HIP_MEMORY_SCOPE_AGENT);
}
// RELEASE-SOUND publish (R6-proven): returning atomic exchange executes AT the
// coherence point before its ack; __syncthreads() (vmcnt 0) then guarantees global
// visibility BEFORE the flag store issues. Plain sc-stores raced (R4/R5).
__device__ __forceinline__ void cx64(void* p, u64 v) {
  u64 old = __hip_atomic_exchange((u64*)p, v, __ATOMIC_RELAXED, __HIP_MEMORY_SCOPE_AGENT);
  asm volatile("" :: "v"(old));
}
__device__ __forceinline__ void cst32(void* p, unsigned v) {
  __hip_atomic_store((unsigned*)p, v, __ATOMIC_RELAXED, __HIP_MEMORY_SCOPE_AGENT);
}

// ===================== convert f32 inputs -> canonical bf16 + state init =====================
__global__ void k_conv(const float* __restrict__ x, const float* __restrict__ w1,
                       const float* __restrict__ w2, const float* __restrict__ ww,
                       const float* __restrict__ pw,
                       u16* __restrict__ Xb, u16* __restrict__ Wc,
                       float* __restrict__ Hf, u16* __restrict__ Hb,
                       float* __restrict__ sums, unsigned* __restrict__ flags,
                       unsigned* __restrict__ poison)
{
  long gid = (long)blockIdx.x * blockDim.x + threadIdx.x;
  const long N0 = 4194304, N1 = 1048576, N2 = 1048576, N3 = 524288, N4 = 524288;
  const long T = N0 + N1 + N2 + N3 + N4;
  for (long p = gid; p < T; p += (long)gridDim.x * blockDim.x) {
    long q = p;
    if (q < N0) { Xb[q] = f2bf(x[q]); continue; }
    q -= N0;
    if (q < N1) { Wc[q] = f2bf(w1[q]); continue; }
    q -= N1;
    if (q < N2) { Wc[N1 + q] = f2bf(w2[q]); continue; }
    q -= N2;
    if (q < N3) { Wc[N1 + N2 + q] = f2bf(ww[q]); continue; }
    q -= N3;
    Wc[N1 + N2 + N3 + q] = f2bf(pw[q]);
  }
  if (gid < 32768) flags[gid] = 0;                      // 4 x 512 x 16 flag words
  if (gid < 2 * Bm * Dm) Hf[gid] = 0.f;
  if (gid < 262144) Hb[gid] = 0;                        // 2 layers x 8 slots x 16384
  if (gid < 16) sums[gid] = 0.f;
  if (gid == 0) *poison = 0;
}

// ===================== fused GEMM (reflection / phi) =====================
// MODE 0: T1 = gelu(rmsnorm(A@W^T+b)*nw)          (bf16 out)
// MODE 1: XrefB = Xres + rw*(rmsnorm(A@W^T+b)*nw - Xres), hi/lo planes, seq-major
// MODE 2: sumdst[b] += ||A@W^T+b||_2 per token row (N=512)
template<int MODE>
__global__ __launch_bounds__(512)
void k_gemm(const u16* __restrict__ A, const u16* __restrict__ W,
            const float* __restrict__ bias, const float* __restrict__ nw,
            const u16* __restrict__ XresB, const float* __restrict__ rwp,
            u16* __restrict__ out0, float* __restrict__ sumdst, int Ncols)
{
  __shared__ u16 At[16 * 1024];
  __shared__ float rowsq[16];
  const int tid = threadIdx.x;
  const int lane = tid & 63, wv = tid >> 6;
  const int rlo = lane & 15, khi = lane >> 4;
  const int m0 = blockIdx.x * 16;

  { // stage 16x1024 bf16 A tile into XOR-swizzled LDS
    int row = tid & 15, c = tid >> 4;   // c in [0,32)
    const char* src = (const char*)(A + (long)(m0 + row) * Dm);
    char* dst = (char*)At + row * 2048;
    int sw = (row & 7) << 4;
#pragma unroll
    for (int i = 0; i < 4; ++i) {
      int bo = c * 64 + i * 16;
      s16x8 v = *(const s16x8*)(src + bo);
      *(s16x8*)(dst + (bo ^ sw)) = v;
    }
  }
  __syncthreads();

  const int j0 = wv * 128;
  const bool act = j0 < Ncols;
  f32x4 zero4 = {0.f, 0.f, 0.f, 0.f};
  f32x4 acc[8];
#pragma unroll
  for (int jt = 0; jt < 8; ++jt) acc[jt] = zero4;

  if (act) {
    const u16* wbase = W + (long)(j0 + rlo) * Dm + khi * 8;
    const char* abase = (const char*)At + rlo * 2048;
    const int asw = (rlo & 7) << 4;
#pragma unroll
    for (int ks = 0; ks < 32; ++ks) {
      s16x8 a = *(const s16x8*)(abase + (((ks * 32 + khi * 8) * 2) ^ asw));
#pragma unroll
      for (int jt = 0; jt < 8; ++jt) {
        s16x8 b = *(const s16x8*)(wbase + (long)jt * 16 * Dm + ks * 32);
        acc[jt] = __builtin_amdgcn_mfma_f32_16x16x32_bf16(a, b, acc[jt], 0, 0, 0);
      }
    }
  }

  if (tid < 16) rowsq[tid] = 0.f;
  __syncthreads();

  float vals[8][4];
  if (act) {
    float rs[4] = {0.f, 0.f, 0.f, 0.f};
#pragma unroll
    for (int jt = 0; jt < 8; ++jt) {
      float bj = bias[j0 + jt * 16 + rlo];
#pragma unroll
      for (int r = 0; r < 4; ++r) {
        float v = acc[jt][r] + bj;
        vals[jt][r] = v;
        rs[r] += v * v;
      }
    }
#pragma unroll
    for (int r = 0; r < 4; ++r) {
#pragma unroll
      for (int m = 1; m < 16; m <<= 1) rs[r] += __shfl_xor(rs[r], m, 64);
    }
    if (rlo == 0) {
#pragma unroll
      for (int r = 0; r < 4; ++r) atomicAdd(&rowsq[khi * 4 + r], rs[r]);
    }
  }
  __syncthreads();

  if constexpr (MODE == 2) {
    if (tid < 16) {
      int token = m0 + tid;
      atomicAdd(&sumdst[token >> 9], sqrtf(rowsq[tid]));
    }
    return;
  } else {
    float rw = 0.f;
    if constexpr (MODE == 1) rw = rwp[0];
    if (act) {
#pragma unroll
      for (int jt = 0; jt < 8; ++jt) {
        int col = j0 + jt * 16 + rlo;
        float nwv = nw[col];
#pragma unroll
        for (int r = 0; r < 4; ++r) {
          int row = khi * 4 + r;
          int token = m0 + row;
          float ms = rowsq[row] * (1.f / 1024.f) + 1.1920929e-07f;
          float y = vals[jt][r] * rsqrtf(ms) * nwv;
          if constexpr (MODE == 0) {
            y = 0.5f * y * (1.f + erff(y * 0.7071067811865476f));
            out0[(long)token * Dm + col] = f2bf(y);
          } else {
            float xf = bf2f(XresB[(long)token * Dm + col]);
            float xr = xf + rw * (y - xf);
            u16 hi = f2bf(xr);
            float lo = xr - bf2f(hi);
            int s = token & (Sm - 1), b = token >> 9;
            long base = ((long)s * 16 + b) * Dm + col;   // [s][plane*8+b][col]
            out0[base] = hi;
            out0[base + 8 * Dm] = f2bf(lo);
          }
        }
      }
    }
  }
}

// ===================== wave-0 spin: per-lane ptr + optional broadcast word =====================
#define SPIN_CAP 2000000

__device__ __forceinline__ bool spin2(const unsigned* pA, bool enA, const unsigned* pB,
                                      unsigned val, unsigned* poison) {
  int spins = 0;
  while (true) {
    bool c = !enA || (__hip_atomic_load(pA, __ATOMIC_RELAXED, __HIP_MEMORY_SCOPE_AGENT) >= val);
    if (pB) c = c && (__hip_atomic_load(pB, __ATOMIC_RELAXED, __HIP_MEMORY_SCOPE_AGENT) >= val);
    if (__all(c)) return true;
    __builtin_amdgcn_s_sleep(1);
    if ((++spins & 255) == 0) {
      if (__hip_atomic_load(poison, __ATOMIC_RELAXED, __HIP_MEMORY_SCOPE_AGENT)) return false;
      if (spins > SPIN_CAP) {
        __hip_atomic_store(poison, 1u, __ATOMIC_RELAXED, __HIP_MEMORY_SCOPE_AGENT);
        return false;
      }
    }
  }
}

// ===================== persistent pipelined GRU (one outer loop) =====================
// R11 = R10 protocol/topology with WIDE consumer WGs to halve coherent-fabric traffic:
//  - 64 WGs x 512 thr (8 waves), 4 roles x 16 WGs, WG owns 64 cols (d0 = w*64).
//  - wave q = K-eighth [q*128, q*128+128): weights bfr[4][3][4] = 192 VGPRs/wave.
//    Per-WG coherent read stays 32KB (exact tile) => per role 16x32KB = 512KB/step
//    (was 1MB with 32 narrow WGs). Total coherent staging 3MB -> 1.5MB per step.
//  - 8 K-partials reduced in two LDS passes (waves 0-3 write, waves 4-7 +=),
//    jt processed in 2 groups to keep acc regs at 24.
//  - direct coherent register loads (no LDS staging), wave-0-only polling (R10).
// Channels (flag arrays now [512][16]):
//   F0[t][w]: role0-w -> role1-w   (gi0 slot t&7)            p2p
//   F1[t][w]: role1-w -> role1/role2 all (h0(t)), role0-w (gi ring guard)
//   F2[t][w]: role2-w -> role3-w   (gi1 slot t&7), role1 (Hb0 slot guard)
//   F3[t][w]: role3-w -> role3 all (h1(t)), role2 (gi1 ring guard)
// Publish: cx64 exchange + __syncthreads + flag (R6-proven, fence-free).
__global__ __launch_bounds__(512, 2)
void k_rec(const float* __restrict__ wih0, const float* __restrict__ whh0,
           const float* __restrict__ bih0, const float* __restrict__ bhh0,
           const float* __restrict__ wih1, const float* __restrict__ whh1,
           const float* __restrict__ bih1, const float* __restrict__ bhh1,
           const u16* __restrict__ XrefB,
           float* __restrict__ gi0r, float* __restrict__ gi1r,
           u16* __restrict__ Hb, float* __restrict__ Hf,
           u16* __restrict__ Xb, float* __restrict__ outx,
           unsigned* __restrict__ flags, unsigned* __restrict__ poison, int loop)
{
  __shared__ float part[4][3][16][65];
  __shared__ unsigned pflag;

  const int wg = blockIdx.x;
  const int role = wg >> 4;          // 4 roles x 16 WGs
  const int w = wg & 15;
  const int d0 = w * 64;
  const int tid = threadIdx.x;
  const int lane = tid & 63, q = tid >> 6;   // q = wave = K-eighth
  const int rlo = lane & 15, khi = lane >> 4;
  const unsigned val = (unsigned)loop + 1u;

  unsigned* F0 = flags;              // [512][16] each
  unsigned* F1 = flags + 8192;
  unsigned* F2 = flags + 16384;
  unsigned* F3 = flags + 24576;
  u16* Hb0 = Hb;                     // [8][16384]: r*1024+col, hi rows 0-7, lo rows 8-15
  u16* Hb1 = Hb + 8 * 16384;

  if (tid == 0) pflag = 0;

  const float* Wsel = (role == 0) ? wih0 : (role == 1) ? whh0 : (role == 2) ? wih1 : whh1;

  // weight fragments: [ks within wave's K-eighth][gate][jtile], f32->bf16 at preload
  s16x8 bfr[4][3][4];
#pragma unroll
  for (int ks = 0; ks < 4; ++ks)
#pragma unroll
    for (int g = 0; g < 3; ++g)
#pragma unroll
      for (int jt = 0; jt < 4; ++jt) {
        int rowj = g * 1024 + d0 + jt * 16 + rlo;
        const float* p = Wsel + (long)rowj * Dm + q * 128 + ks * 32 + khi * 8;
        s16x8 f;
#pragma unroll
        for (int e = 0; e < 8; ++e) f[e] = (short)f2bf(p[e]);
        bfr[ks][g][jt] = f;
      }

  // per-thread output-phase constants & register state: thread = (b = q, dd = lane)
  const int ob = q, odd = lane, od = d0 + odd;
  float bias_r[3];
  {
    const float* bsel = (role == 0) ? bih0 : (role == 1) ? bhh0 : (role == 2) ? bih1 : bhh1;
#pragma unroll
    for (int g = 0; g < 3; ++g) bias_r[g] = bsel[g * 1024 + od];
  }
  const int layer = (role == 1) ? 0 : 1;
  float hreg = 0.f;
  if (role == 1 || role == 3) hreg = Hf[layer * 8192 + ob * 1024 + od];
  __syncthreads();

  for (int t = 0; t < Sm; ++t) {
    // ---- wave-0-only dependency wait ----
    if (q == 0) {
      bool need = true;
      const unsigned* pA;
      const unsigned* pB = nullptr;
      bool enA;
      if (role == 0) {
        pA = &F1[((t >= 8) ? (t - 8) : 0) * 16 + w];
        enA = (lane == 0);
        need = (t >= 8);
      } else if (role == 1) {
        pA = (lane < 16) ? &F1[((t >= 1) ? (t - 1) : 0) * 16 + lane]
           : (lane < 32) ? &F2[((t >= 8) ? (t - 8) : 0) * 16 + (lane - 16)]
                         : &F0[t * 16 + w];
        enA = (lane < 16) ? (t >= 1) : (lane < 32) ? (t >= 8) : false;
        pB = &F0[t * 16 + w];
      } else if (role == 2) {
        pA = &F1[t * 16 + ((lane < 16) ? lane : 0)];
        enA = (lane < 16);
        pB = (t >= 8) ? &F3[(t - 8) * 16 + w] : nullptr;
      } else {
        pA = &F3[((t >= 1) ? (t - 1) : 0) * 16 + ((lane < 16) ? lane : 0)];
        enA = (lane < 16) && (t >= 1);
        pB = &F2[t * 16 + w];
      }
      if (need) {
        if (!spin2(pA, enA, pB, val, poison)) { if (lane == 0) pflag = 1; }
      }
    }
    __builtin_amdgcn_sched_barrier(0);   // pin: nothing moves above the wait
    __syncthreads();
    if (pflag) return;

    // ---- gi prefetch (roles 1,3): after flag observation, overlaps MFMA ----
    float giv[3] = {0.f, 0.f, 0.f};
    if (role == 1 || role == 3) {
      const float* ring = ((role == 1) ? gi0r : gi1r) + ((long)(t & 7) * Bm + ob) * 3072 + od;
      giv[0] = cldf(ring);
      giv[1] = cldf(ring + 1024);
      giv[2] = cldf(ring + 2048);
    }

    // ---- direct A-fragment loads (no LDS): wave q covers K [q*128, q*128+128) ----
    s16x8 areg[4];
    if (role == 0) {
      const u16* src = XrefB + (long)t * 16 * Dm + rlo * 1024 + q * 128 + khi * 8;
#pragma unroll
      for (int ks = 0; ks < 4; ++ks)
        areg[ks] = *(const s16x8*)(src + ks * 32);     // cached 16B loads
    } else {
      const u16* base = (role == 1) ? Hb0 + ((t - 1) & 7) * 16384
                      : (role == 2) ? Hb0 + (t & 7) * 16384
                                    : Hb1 + ((t - 1) & 7) * 16384;
      const u16* src = base + rlo * 1024 + q * 128 + khi * 8;
#pragma unroll
      for (int ks = 0; ks < 4; ++ks) {
        union { u64 u[2]; s16x8 v; } tmp;
        tmp.u[0] = cld64(src + ks * 32);               // coherent 8B loads
        tmp.u[1] = cld64(src + ks * 32 + 4);
        areg[ks] = tmp.v;
      }
    }

    // ---- MFMA + two-pass 8-partial reduction, jt processed in 2 groups ----
    f32x4 zero4 = {0.f, 0.f, 0.f, 0.f};
#pragma unroll
    for (int jg = 0; jg < 2; ++jg) {
      f32x4 acc[3][2];
#pragma unroll
      for (int g = 0; g < 3; ++g) { acc[g][0] = zero4; acc[g][1] = zero4; }
#pragma unroll
      for (int ks = 0; ks < 4; ++ks)
#pragma unroll
        for (int g = 0; g < 3; ++g)
#pragma unroll
          for (int j2 = 0; j2 < 2; ++j2)
            acc[g][j2] = __builtin_amdgcn_mfma_f32_16x16x32_bf16(
                areg[ks], bfr[ks][g][jg * 2 + j2], acc[g][j2], 0, 0, 0);
      if (q < 4) {
#pragma unroll
        for (int g = 0; g < 3; ++g)
#pragma unroll
          for (int j2 = 0; j2 < 2; ++j2)
#pragma unroll
            for (int r = 0; r < 4; ++r)
              part[q][g][khi * 4 + r][jg * 32 + j2 * 16 + rlo] = acc[g][j2][r];
      }
      __syncthreads();
      if (q >= 4) {
#pragma unroll
        for (int g = 0; g < 3; ++g)
#pragma unroll
          for (int j2 = 0; j2 < 2; ++j2)
#pragma unroll
            for (int r = 0; r < 4; ++r)
              part[q - 4][g][khi * 4 + r][jg * 32 + j2 * 16 + rlo] += acc[g][j2][r];
      }
      __syncthreads();
    }

    { // ---- output phase: thread = (b = q, dd = lane) over 8 x 64 ----
      int b = ob, dd = odd;
      float v[3];
#pragma unroll
      for (int g = 0; g < 3; ++g) {
        float sv = 0.f;
#pragma unroll
        for (int p = 0; p < 4; ++p)
          sv += part[p][g][b][dd] + part[p][g][8 + b][dd];   // hi + lo rows
        v[g] = sv;
      }
      if (role == 0 || role == 2) {
        float* ring = ((role == 0) ? gi0r : gi1r) + ((long)(t & 7) * Bm + b) * 3072 + od;
#pragma unroll
        for (int g = 0; g < 3; ++g) {
          float fg = v[g] + bias_r[g];
          float pg = __shfl_xor(fg, 1, 64);
          if ((dd & 1) == 0) {
            union { float f; unsigned u; } a0, a1;
            a0.f = fg; a1.f = pg;
            u64 pk = (u64)a0.u | ((u64)a1.u << 32);
            cx64(ring + g * 1024, pk);               // RELEASE-SOUND publish (pair)
          }
        }
      } else {
        float gr = giv[0] + v[0] + bias_r[0];
        float gz = giv[1] + v[1] + bias_r[1];
        float ghn = v[2] + bias_r[2];
        float rr = sigm(gr), zz = sigm(gz);
        float nn = tanhf(giv[2] + rr * ghn);
        float hn = (1.f - zz) * nn + zz * hreg;
        hreg = hn;
        u16 hi = f2bf(hn);
        u16 lo = f2bf(hn - bf2f(hi));
        // quad-pack 4 adjacent columns -> 2 u64 exchanges per 4 lanes
        unsigned myv = (unsigned)hi | ((unsigned)lo << 16);
        unsigned p1 = __shfl_xor(myv, 1, 64);
        unsigned hiPair = (myv & 0xFFFFu) | ((p1 & 0xFFFFu) << 16);
        unsigned loPair = (myv >> 16) | (p1 & 0xFFFF0000u);
        unsigned hp2 = __shfl_xor(hiPair, 2, 64);
        unsigned lp2 = __shfl_xor(loPair, 2, 64);
        if ((dd & 3) == 0) {
          u64 hq = (u64)hiPair | ((u64)hp2 << 32);
          u64 lq = (u64)loPair | ((u64)lp2 << 32);
          u16* hb = ((role == 1) ? Hb0 : Hb1) + (t & 7) * 16384;
          cx64(hb + b * 1024 + od, hq);               // RELEASE-SOUND publish (quad)
          cx64(hb + 8192 + b * 1024 + od, lq);
        }
        if (role == 3) {
          long xi = ((long)b * Sm + t) * Dm + od;
          Xb[xi] = hi;                 // consumed by next dispatch (normal store)
          if (outx) outx[xi] = hn;
        }
        if (t == Sm - 1) Hf[layer * 8192 + b * 1024 + od] = hreg;
      }
    }
    __syncthreads();        // vmcnt(0): all exchanges executed at coherence point
    __builtin_amdgcn_sched_barrier(0);   // pin: flag store cannot move above
    if (tid == 0) {
      unsigned* F = (role == 0) ? F0 : (role == 1) ? F1 : (role == 2) ? F2 : F3;
      cst32(&F[t * 16 + w], val);
    }
  }
}

// ===================== final phi =====================
__global__ void k_phi(const float* __restrict__ sums, const float* __restrict__ psc,
                      const float* __restrict__ pbi, float* __restrict__ out)
{
  int b = threadIdx.x;
  if (b < 8) {
    float whole = sums[8 + b] * (1.f / 512.f);
    float parts = sums[b] * (1.f / 1024.f);
    float raw = (whole - parts) / (whole + 1e-8f);
    float phi = psc[0] * raw + pbi[0];
    phi = fminf(fmaxf(phi, 0.f), 1.f);
    out[(long)Bm * Sm * Dm + b] = phi;
  }
}

// ===================== host =====================
extern "C" void kernel_launch(void* const* d_in, const int* in_sizes, int n_in,
                              void* d_out, int out_size, void* d_ws, size_t ws_size,
                              hipStream_t stream)
{
  (void)in_sizes; (void)n_in; (void)out_size;
  const float* b1   = (const float*)d_in[2];
  const float* r1w  = (const float*)d_in[3];
  const float* b2   = (const float*)d_in[5];
  const float* r2w  = (const float*)d_in[6];
  const float* rw   = (const float*)d_in[7];
  const float* wb   = (const float*)d_in[9];
  const float* pb   = (const float*)d_in[11];
  const float* psc  = (const float*)d_in[12];
  const float* pbi  = (const float*)d_in[13];
  const float* wih0 = (const float*)d_in[14];
  const float* whh0 = (const float*)d_in[15];
  const float* bih0 = (const float*)d_in[16];
  const float* bhh0 = (const float*)d_in[17];
  const float* wih1 = (const float*)d_in[18];
  const float* whh1 = (const float*)d_in[19];
  const float* bih1 = (const float*)d_in[20];
  const float* bhh1 = (const float*)d_in[21];
  float* out = (float*)d_out;

  if (ws_size < 45000000) return;

  char* ws = (char*)d_ws;
  size_t off = 0;
  auto alloc = [&](size_t bytes) -> char* {
    char* p = ws + off;
    off += (bytes + 255) & ~(size_t)255;
    return p;
  };
  u16*      Xb    = (u16*)  alloc((size_t)4194304 * 2);
  u16*      T1    = (u16*)  alloc((size_t)4194304 * 2);
  u16*      XrefB = (u16*)  alloc((size_t)2 * 4194304 * 2);   // [S][16 rows][1024] hi/lo
  float*    gi0r  = (float*)alloc((size_t)8 * 8 * 3072 * 4);  // depth-8 ring
  float*    gi1r  = (float*)alloc((size_t)8 * 8 * 3072 * 4);
  u16*      Hb    = (u16*)  alloc((size_t)2 * 8 * 16384 * 2); // 2 layers x 8-slot ring
  float*    Hf    = (float*)alloc((size_t)2 * 8192 * 4);
  u16*      Wc    = (u16*)  alloc((size_t)3145728 * 2);       // [w1|w2|ww|pw] bf16
  float*    sums  = (float*)alloc(16 * 4);
  unsigned* flags = (unsigned*)alloc((size_t)32768 * 4);      // F0|F1|F2|F3, [512][16] each
  unsigned* poi   = (unsigned*)alloc(256);

  u16* WcW1 = Wc;
  u16* WcW2 = Wc + 1048576;
  u16* WcWW = Wc + 2097152;
  u16* WcPW = Wc + 2621440;

  k_conv<<<2048, 256, 0, stream>>>((const float*)d_in[0], (const float*)d_in[1],
                                   (const float*)d_in[4], (const float*)d_in[8],
                                   (const float*)d_in[10],
                                   Xb, Wc, Hf, Hb, sums, flags, poi);

  for (int loop = 0; loop < 3; ++loop) {
    k_gemm<0><<<256, 512, 0, stream>>>(Xb, WcW1, b1, r1w, nullptr, nullptr, T1, nullptr, 1024);
    k_gemm<1><<<256, 512, 0, stream>>>(T1, WcW2, b2, r2w, Xb, rw, XrefB, nullptr, 1024);
    k_rec<<<64, 512, 0, stream>>>(wih0, whh0, bih0, bhh0, wih1, whh1, bih1, bhh1,
                                  XrefB, gi0r, gi1r, Hb, Hf, Xb,
                                  (loop == 2) ? out : nullptr, flags, poi, loop);
    if (loop < 2)
      k_gemm<2><<<256, 512, 0, stream>>>(Xb, WcPW, pb, nullptr, nullptr, nullptr, nullptr, sums, 512);
    else
      k_gemm<2><<<256, 512, 0, stream>>>(Xb, WcWW, wb, nullptr, nullptr, nullptr, nullptr, sums + 8, 512);
  }
  k_phi<<<1, 64, 0, stream>>>(sums, psc, pbi, out);
}

// Round 12
// 10352.052 us; speedup vs baseline: 1.2749x; 1.2749x over previous
//
#include <hip/hip_runtime.h>
#include <math.h>

#define Dm 1024
#define Bm 8
#define Sm 512

typedef short s16x8 __attribute__((ext_vector_type(8)));
typedef float f32x4 __attribute__((ext_vector_type(4)));
typedef unsigned short u16;
typedef unsigned long long u64;

__device__ __forceinline__ float bf2f(u16 u) {
  union { float f; unsigned v; } x; x.v = (unsigned)u << 16; return x.f;
}
__device__ __forceinline__ u16 f2bf(float f) {
  union { float f; unsigned v; } x; x.f = f;
  unsigned r = x.v + 0x7FFFu + ((x.v >> 16) & 1u);
  return (u16)(r >> 16);
}
__device__ __forceinline__ float sigm(float x) { return 1.f / (1.f + expf(-x)); }

// coherent (agent-scope) access helpers
__device__ __forceinline__ u64 cld64(const void* p) {
  return __hip_atomic_load((const u64*)p, __ATOMIC_RELAXED, __HIP_MEMORY_SCOPE_AGENT);
}
__device__ __forceinline__ float cldf(const void* p) {
  return __hip_atomic_load((const float*)p, __ATOMIC_RELAXED, __HIP_MEMORY_SCOPE_AGENT);
}
// RELEASE-SOUND publish (R6-proven): returning atomic exchange executes AT the
// coherence point before its ack; __syncthreads() (vmcnt 0) then guarantees global
// visibility BEFORE the signal issues. Plain sc-stores raced (R4/R5).
__device__ __forceinline__ void cx64(void* p, u64 v) {
  u64 old = __hip_atomic_exchange((u64*)p, v, __ATOMIC_RELAXED, __HIP_MEMORY_SCOPE_AGENT);
  asm volatile("" :: "v"(old));
}
__device__ __forceinline__ void cst32(void* p, unsigned v) {
  __hip_atomic_store((unsigned*)p, v, __ATOMIC_RELAXED, __HIP_MEMORY_SCOPE_AGENT);
}
__device__ __forceinline__ void cadd32(void* p) {
  __hip_atomic_fetch_add((unsigned*)p, 1u, __ATOMIC_RELAXED, __HIP_MEMORY_SCOPE_AGENT);
}

#define FLAGS_TOTAL 67072   // F0|F1|F2|F3 ([512][32] each) + cnt1|cnt2|cnt3 ([512] each, padded)

// ===================== convert f32 inputs -> canonical bf16 + state init =====================
__global__ void k_conv(const float* __restrict__ x, const float* __restrict__ w1,
                       const float* __restrict__ w2, const float* __restrict__ ww,
                       const float* __restrict__ pw,
                       u16* __restrict__ Xb, u16* __restrict__ Wc,
                       float* __restrict__ Hf, u16* __restrict__ Hb,
                       float* __restrict__ sums, unsigned* __restrict__ flags,
                       unsigned* __restrict__ poison)
{
  long gid = (long)blockIdx.x * blockDim.x + threadIdx.x;
  const long N0 = 4194304, N1 = 1048576, N2 = 1048576, N3 = 524288, N4 = 524288;
  const long T = N0 + N1 + N2 + N3 + N4;
  for (long p = gid; p < T; p += (long)gridDim.x * blockDim.x) {
    long q = p;
    if (q < N0) { Xb[q] = f2bf(x[q]); continue; }
    q -= N0;
    if (q < N1) { Wc[q] = f2bf(w1[q]); continue; }
    q -= N1;
    if (q < N2) { Wc[N1 + q] = f2bf(w2[q]); continue; }
    q -= N2;
    if (q < N3) { Wc[N1 + N2 + q] = f2bf(ww[q]); continue; }
    q -= N3;
    Wc[N1 + N2 + N3 + q] = f2bf(pw[q]);
  }
  if (gid < FLAGS_TOTAL) flags[gid] = 0;
  if (gid < 2 * Bm * Dm) Hf[gid] = 0.f;
  if (gid < 262144) Hb[gid] = 0;                        // 2 layers x 8 slots x 16384
  if (gid < 16) sums[gid] = 0.f;
  if (gid == 0) *poison = 0;
}

// ===================== fused GEMM (reflection / phi) =====================
// MODE 0: T1 = gelu(rmsnorm(A@W^T+b)*nw)          (bf16 out)
// MODE 1: XrefB = Xres + rw*(rmsnorm(A@W^T+b)*nw - Xres), hi/lo planes, seq-major
// MODE 2: sumdst[b] += ||A@W^T+b||_2 per token row (N=512)
template<int MODE>
__global__ __launch_bounds__(512)
void k_gemm(const u16* __restrict__ A, const u16* __restrict__ W,
            const float* __restrict__ bias, const float* __restrict__ nw,
            const u16* __restrict__ XresB, const float* __restrict__ rwp,
            u16* __restrict__ out0, float* __restrict__ sumdst, int Ncols)
{
  __shared__ u16 At[16 * 1024];
  __shared__ float rowsq[16];
  const int tid = threadIdx.x;
  const int lane = tid & 63, wv = tid >> 6;
  const int rlo = lane & 15, khi = lane >> 4;
  const int m0 = blockIdx.x * 16;

  { // stage 16x1024 bf16 A tile into XOR-swizzled LDS
    int row = tid & 15, c = tid >> 4;   // c in [0,32)
    const char* src = (const char*)(A + (long)(m0 + row) * Dm);
    char* dst = (char*)At + row * 2048;
    int sw = (row & 7) << 4;
#pragma unroll
    for (int i = 0; i < 4; ++i) {
      int bo = c * 64 + i * 16;
      s16x8 v = *(const s16x8*)(src + bo);
      *(s16x8*)(dst + (bo ^ sw)) = v;
    }
  }
  __syncthreads();

  const int j0 = wv * 128;
  const bool act = j0 < Ncols;
  f32x4 zero4 = {0.f, 0.f, 0.f, 0.f};
  f32x4 acc[8];
#pragma unroll
  for (int jt = 0; jt < 8; ++jt) acc[jt] = zero4;

  if (act) {
    const u16* wbase = W + (long)(j0 + rlo) * Dm + khi * 8;
    const char* abase = (const char*)At + rlo * 2048;
    const int asw = (rlo & 7) << 4;
#pragma unroll
    for (int ks = 0; ks < 32; ++ks) {
      s16x8 a = *(const s16x8*)(abase + (((ks * 32 + khi * 8) * 2) ^ asw));
#pragma unroll
      for (int jt = 0; jt < 8; ++jt) {
        s16x8 b = *(const s16x8*)(wbase + (long)jt * 16 * Dm + ks * 32);
        acc[jt] = __builtin_amdgcn_mfma_f32_16x16x32_bf16(a, b, acc[jt], 0, 0, 0);
      }
    }
  }

  if (tid < 16) rowsq[tid] = 0.f;
  __syncthreads();

  float vals[8][4];
  if (act) {
    float rs[4] = {0.f, 0.f, 0.f, 0.f};
#pragma unroll
    for (int jt = 0; jt < 8; ++jt) {
      float bj = bias[j0 + jt * 16 + rlo];
#pragma unroll
      for (int r = 0; r < 4; ++r) {
        float v = acc[jt][r] + bj;
        vals[jt][r] = v;
        rs[r] += v * v;
      }
    }
#pragma unroll
    for (int r = 0; r < 4; ++r) {
#pragma unroll
      for (int m = 1; m < 16; m <<= 1) rs[r] += __shfl_xor(rs[r], m, 64);
    }
    if (rlo == 0) {
#pragma unroll
      for (int r = 0; r < 4; ++r) atomicAdd(&rowsq[khi * 4 + r], rs[r]);
    }
  }
  __syncthreads();

  if constexpr (MODE == 2) {
    if (tid < 16) {
      int token = m0 + tid;
      atomicAdd(&sumdst[token >> 9], sqrtf(rowsq[tid]));
    }
    return;
  } else {
    float rw = 0.f;
    if constexpr (MODE == 1) rw = rwp[0];
    if (act) {
#pragma unroll
      for (int jt = 0; jt < 8; ++jt) {
        int col = j0 + jt * 16 + rlo;
        float nwv = nw[col];
#pragma unroll
        for (int r = 0; r < 4; ++r) {
          int row = khi * 4 + r;
          int token = m0 + row;
          float ms = rowsq[row] * (1.f / 1024.f) + 1.1920929e-07f;
          float y = vals[jt][r] * rsqrtf(ms) * nwv;
          if constexpr (MODE == 0) {
            y = 0.5f * y * (1.f + erff(y * 0.7071067811865476f));
            out0[(long)token * Dm + col] = f2bf(y);
          } else {
            float xf = bf2f(XresB[(long)token * Dm + col]);
            float xr = xf + rw * (y - xf);
            u16 hi = f2bf(xr);
            float lo = xr - bf2f(hi);
            int s = token & (Sm - 1), b = token >> 9;
            long base = ((long)s * 16 + b) * Dm + col;   // [s][plane*8+b][col]
            out0[base] = hi;
            out0[base + 8 * Dm] = f2bf(lo);
          }
        }
      }
    }
  }
}

// ===================== wave-0 spin on up to 3 uniform words =====================
#define SPIN_CAP 2000000

__device__ __forceinline__ bool spin3(const unsigned* p0, bool e0, unsigned v0,
                                      const unsigned* p1, bool e1, unsigned v1,
                                      const unsigned* p2, bool e2, unsigned v2,
                                      unsigned* poison) {
  int spins = 0;
  while (true) {
    bool c = true;
    if (e0) c = c && (__hip_atomic_load(p0, __ATOMIC_RELAXED, __HIP_MEMORY_SCOPE_AGENT) >= v0);
    if (e1) c = c && (__hip_atomic_load(p1, __ATOMIC_RELAXED, __HIP_MEMORY_SCOPE_AGENT) >= v1);
    if (e2) c = c && (__hip_atomic_load(p2, __ATOMIC_RELAXED, __HIP_MEMORY_SCOPE_AGENT) >= v2);
    if (__all(c)) return true;
    __builtin_amdgcn_s_sleep(2);
    if ((++spins & 255) == 0) {
      if (__hip_atomic_load(poison, __ATOMIC_RELAXED, __HIP_MEMORY_SCOPE_AGENT)) return false;
      if (spins > SPIN_CAP) {
        __hip_atomic_store(poison, 1u, __ATOMIC_RELAXED, __HIP_MEMORY_SCOPE_AGENT);
        return false;
      }
    }
  }
}

// ===================== persistent pipelined GRU (one outer loop) =====================
// R12 = R10 (128 WGs x 256 thr, 4 roles x 32 WGs, direct coherent register loads,
// wave-0-only polling) with GATHERED FLAGS COLLAPSED TO PER-CHANNEL COUNTERS:
// producers role1/2/3 signal via one atomicAdd(cnt[chan][t]); consumers poll ONE
// word for cnt >= 32*val (monotonic across the 3 dispatches). P2p flags (F0, F2,
// F1-per-w for role0's ring guard) stay per-word. Cuts IC poll congestion ~32x.
// Waits:
//   role0: F1[t-8][w]                              (gi0 ring guard, p2p)
//   role1: F0[t][w] + cnt1[t-1] + cnt2[t-8]        (gi0 ready; peers; Hb0 slot guard)
//   role2: cnt1[t] + cnt3[t-8]                     (h0 ready; gi1 ring guard)
//   role3: F2[t][w] + cnt3[t-1]                    (gi1 ready; peers)
// Publish (tid0, after cx64 exchanges + syncthreads): role0 F0[t][w]; role1 F1[t][w]
// + cnt1[t]++; role2 F2[t][w] + cnt2[t]++; role3 cnt3[t]++.
__global__ __launch_bounds__(256, 1)
void k_rec(const float* __restrict__ wih0, const float* __restrict__ whh0,
           const float* __restrict__ bih0, const float* __restrict__ bhh0,
           const float* __restrict__ wih1, const float* __restrict__ whh1,
           const float* __restrict__ bih1, const float* __restrict__ bhh1,
           const u16* __restrict__ XrefB,
           float* __restrict__ gi0r, float* __restrict__ gi1r,
           u16* __restrict__ Hb, float* __restrict__ Hf,
           u16* __restrict__ Xb, float* __restrict__ outx,
           unsigned* __restrict__ flags, unsigned* __restrict__ poison, int loop)
{
  __shared__ float part[4][3][16][33];
  __shared__ unsigned pflag;

  const int wg = blockIdx.x;
  const int role = wg >> 5;
  const int w = wg & 31;
  const int d0 = w * 32;
  const int tid = threadIdx.x;
  const int lane = tid & 63, q = tid >> 6;
  const int rlo = lane & 15, khi = lane >> 4;
  const unsigned val = (unsigned)loop + 1u;
  const unsigned cval = 32u * val;

  unsigned* F0 = flags;
  unsigned* F1 = flags + 16384;
  unsigned* F2 = flags + 32768;
  unsigned* cnt1 = flags + 65536;
  unsigned* cnt2 = flags + 66048;
  unsigned* cnt3 = flags + 66560;
  u16* Hb0 = Hb;                     // [8][16384]: r*1024+col, hi rows 0-7, lo rows 8-15
  u16* Hb1 = Hb + 8 * 16384;

  if (tid == 0) pflag = 0;

  const float* Wsel = (role == 0) ? wih0 : (role == 1) ? whh0 : (role == 2) ? wih1 : whh1;

  // weight fragments: [kstep in wave's K-quarter][gate][jtile], f32->bf16 at preload
  s16x8 bfr[8][3][2];
#pragma unroll
  for (int ks = 0; ks < 8; ++ks)
#pragma unroll
    for (int g = 0; g < 3; ++g)
#pragma unroll
      for (int jt = 0; jt < 2; ++jt) {
        int rowj = g * 1024 + d0 + jt * 16 + rlo;
        const float* p = Wsel + (long)rowj * Dm + q * 256 + ks * 32 + khi * 8;
        s16x8 f;
#pragma unroll
        for (int e = 0; e < 8; ++e) f[e] = (short)f2bf(p[e]);
        bfr[ks][g][jt] = f;
      }

  // per-thread output-phase constants & register state
  const int ob = tid >> 5, odd = tid & 31, od = d0 + odd;
  float bias_r[3];
  {
    const float* bsel = (role == 0) ? bih0 : (role == 1) ? bhh0 : (role == 2) ? bih1 : bhh1;
#pragma unroll
    for (int g = 0; g < 3; ++g) bias_r[g] = bsel[g * 1024 + od];
  }
  const int layer = (role == 1) ? 0 : 1;
  float hreg = 0.f;
  if (role == 1 || role == 3) hreg = Hf[layer * 8192 + ob * 1024 + od];
  __syncthreads();

  for (int t = 0; t < Sm; ++t) {
    // ---- wave-0-only dependency wait (1-3 uniform words) ----
    if (q == 0) {
      bool okw = true;
      if (role == 0) {
        if (t >= 8)
          okw = spin3(&F1[(t - 8) * 32 + w], true, val,
                      nullptr, false, 0, nullptr, false, 0, poison);
      } else if (role == 1) {
        okw = spin3(&F0[t * 32 + w], true, val,
                    &cnt1[(t >= 1) ? (t - 1) : 0], (t >= 1), cval,
                    &cnt2[(t >= 8) ? (t - 8) : 0], (t >= 8), cval, poison);
      } else if (role == 2) {
        okw = spin3(&cnt1[t], true, cval,
                    &cnt3[(t >= 8) ? (t - 8) : 0], (t >= 8), cval,
                    nullptr, false, 0, poison);
      } else {
        okw = spin3(&F2[t * 32 + w], true, val,
                    &cnt3[(t >= 1) ? (t - 1) : 0], (t >= 1), cval,
                    nullptr, false, 0, poison);
      }
      if (!okw && lane == 0) pflag = 1;
    }
    __builtin_amdgcn_sched_barrier(0);   // pin: nothing moves above the wait
    __syncthreads();
    if (pflag) return;

    // ---- gi prefetch (roles 1,3): after flag observation, overlaps MFMA ----
    float giv[3] = {0.f, 0.f, 0.f};
    if (role == 1 || role == 3) {
      const float* ring = ((role == 1) ? gi0r : gi1r) + ((long)(t & 7) * Bm + ob) * 3072 + od;
      giv[0] = cldf(ring);
      giv[1] = cldf(ring + 1024);
      giv[2] = cldf(ring + 2048);
    }

    // ---- direct A-fragment loads (no LDS) ----
    s16x8 areg[8];
    if (role == 0) {
      const u16* src = XrefB + (long)t * 16 * Dm + rlo * 1024 + q * 256 + khi * 8;
#pragma unroll
      for (int ks = 0; ks < 8; ++ks)
        areg[ks] = *(const s16x8*)(src + ks * 32);     // cached 16B loads
    } else {
      const u16* base = (role == 1) ? Hb0 + ((t - 1) & 7) * 16384
                      : (role == 2) ? Hb0 + (t & 7) * 16384
                                    : Hb1 + ((t - 1) & 7) * 16384;
      const u16* src = base + rlo * 1024 + q * 256 + khi * 8;
#pragma unroll
      for (int ks = 0; ks < 8; ++ks) {
        union { u64 u[2]; s16x8 v; } tmp;
        tmp.u[0] = cld64(src + ks * 32);               // coherent 8B loads
        tmp.u[1] = cld64(src + ks * 32 + 4);
        areg[ks] = tmp.v;
      }
    }

    // ---- MFMA: 16x(d0..d0+31) slice of [hi;lo] @ W^T ----
    f32x4 zero4 = {0.f, 0.f, 0.f, 0.f};
    f32x4 acc[3][2];
#pragma unroll
    for (int g = 0; g < 3; ++g) { acc[g][0] = zero4; acc[g][1] = zero4; }
#pragma unroll
    for (int ks = 0; ks < 8; ++ks)
#pragma unroll
      for (int g = 0; g < 3; ++g)
#pragma unroll
        for (int jt = 0; jt < 2; ++jt)
          acc[g][jt] = __builtin_amdgcn_mfma_f32_16x16x32_bf16(areg[ks], bfr[ks][g][jt], acc[g][jt], 0, 0, 0);

#pragma unroll
    for (int g = 0; g < 3; ++g)
#pragma unroll
      for (int jt = 0; jt < 2; ++jt)
#pragma unroll
        for (int r = 0; r < 4; ++r)
          part[q][g][khi * 4 + r][jt * 16 + rlo] = acc[g][jt][r];
    __syncthreads();

    { // ---- output phase: one thread per (b, dd) ----
      int b = ob, dd = odd;
      float v[3];
#pragma unroll
      for (int g = 0; g < 3; ++g) {
        float sv = 0.f;
#pragma unroll
        for (int qq = 0; qq < 4; ++qq)
          sv += part[qq][g][b][dd] + part[qq][g][8 + b][dd];   // hi + lo rows
        v[g] = sv;
      }
      if (role == 0 || role == 2) {
        float* ring = ((role == 0) ? gi0r : gi1r) + ((long)(t & 7) * Bm + b) * 3072 + od;
#pragma unroll
        for (int g = 0; g < 3; ++g) {
          float fg = v[g] + bias_r[g];
          float pg = __shfl_xor(fg, 1, 64);
          if ((dd & 1) == 0) {
            union { float f; unsigned u; } a0, a1;
            a0.f = fg; a1.f = pg;
            u64 pk = (u64)a0.u | ((u64)a1.u << 32);
            cx64(ring + g * 1024, pk);               // RELEASE-SOUND publish (pair)
          }
        }
      } else {
        float gr = giv[0] + v[0] + bias_r[0];
        float gz = giv[1] + v[1] + bias_r[1];
        float ghn = v[2] + bias_r[2];
        float rr = sigm(gr), zz = sigm(gz);
        float nn = tanhf(giv[2] + rr * ghn);
        float hn = (1.f - zz) * nn + zz * hreg;
        hreg = hn;
        u16 hi = f2bf(hn);
        u16 lo = f2bf(hn - bf2f(hi));
        // quad-pack 4 adjacent columns -> 2 u64 exchanges per 4 lanes
        unsigned myv = (unsigned)hi | ((unsigned)lo << 16);
        unsigned p1 = __shfl_xor(myv, 1, 64);
        unsigned hiPair = (myv & 0xFFFFu) | ((p1 & 0xFFFFu) << 16);
        unsigned loPair = (myv >> 16) | (p1 & 0xFFFF0000u);
        unsigned hp2 = __shfl_xor(hiPair, 2, 64);
        unsigned lp2 = __shfl_xor(loPair, 2, 64);
        if ((dd & 3) == 0) {
          u64 hq = (u64)hiPair | ((u64)hp2 << 32);
          u64 lq = (u64)loPair | ((u64)lp2 << 32);
          u16* hb = ((role == 1) ? Hb0 : Hb1) + (t & 7) * 16384;
          cx64(hb + b * 1024 + od, hq);               // RELEASE-SOUND publish (quad)
          cx64(hb + 8192 + b * 1024 + od, lq);
        }
        if (role == 3) {
          long xi = ((long)b * Sm + t) * Dm + od;
          Xb[xi] = hi;                 // consumed by next dispatch (normal store)
          if (outx) outx[xi] = hn;
        }
        if (t == Sm - 1) Hf[layer * 8192 + b * 1024 + od] = hreg;
      }
    }
    __syncthreads();        // vmcnt(0): all exchanges executed at coherence point
    __builtin_amdgcn_sched_barrier(0);   // pin: signals cannot move above
    if (tid == 0) {
      if (role == 0) {
        cst32(&F0[t * 32 + w], val);
      } else if (role == 1) {
        cst32(&F1[t * 32 + w], val);
        cadd32(&cnt1[t]);
      } else if (role == 2) {
        cst32(&F2[t * 32 + w], val);
        cadd32(&cnt2[t]);
      } else {
        cadd32(&cnt3[t]);
      }
    }
  }
}

// ===================== final phi =====================
__global__ void k_phi(const float* __restrict__ sums, const float* __restrict__ psc,
                      const float* __restrict__ pbi, float* __restrict__ out)
{
  int b = threadIdx.x;
  if (b < 8) {
    float whole = sums[8 + b] * (1.f / 512.f);
    float parts = sums[b] * (1.f / 1024.f);
    float raw = (whole - parts) / (whole + 1e-8f);
    float phi = psc[0] * raw + pbi[0];
    phi = fminf(fmaxf(phi, 0.f), 1.f);
    out[(long)Bm * Sm * Dm + b] = phi;
  }
}

// ===================== host =====================
extern "C" void kernel_launch(void* const* d_in, const int* in_sizes, int n_in,
                              void* d_out, int out_size, void* d_ws, size_t ws_size,
                              hipStream_t stream)
{
  (void)in_sizes; (void)n_in; (void)out_size;
  const float* b1   = (const float*)d_in[2];
  const float* r1w  = (const float*)d_in[3];
  const float* b2   = (const float*)d_in[5];
  const float* r2w  = (const float*)d_in[6];
  const float* rw   = (const float*)d_in[7];
  const float* wb   = (const float*)d_in[9];
  const float* pb   = (const float*)d_in[11];
  const float* psc  = (const float*)d_in[12];
  const float* pbi  = (const float*)d_in[13];
  const float* wih0 = (const float*)d_in[14];
  const float* whh0 = (const float*)d_in[15];
  const float* bih0 = (const float*)d_in[16];
  const float* bhh0 = (const float*)d_in[17];
  const float* wih1 = (const float*)d_in[18];
  const float* whh1 = (const float*)d_in[19];
  const float* bih1 = (const float*)d_in[20];
  const float* bhh1 = (const float*)d_in[21];
  float* out = (float*)d_out;

  if (ws_size < 45000000) return;

  char* ws = (char*)d_ws;
  size_t off = 0;
  auto alloc = [&](size_t bytes) -> char* {
    char* p = ws + off;
    off += (bytes + 255) & ~(size_t)255;
    return p;
  };
  u16*      Xb    = (u16*)  alloc((size_t)4194304 * 2);
  u16*      T1    = (u16*)  alloc((size_t)4194304 * 2);
  u16*      XrefB = (u16*)  alloc((size_t)2 * 4194304 * 2);   // [S][16 rows][1024] hi/lo
  float*    gi0r  = (float*)alloc((size_t)8 * 8 * 3072 * 4);  // depth-8 ring
  float*    gi1r  = (float*)alloc((size_t)8 * 8 * 3072 * 4);
  u16*      Hb    = (u16*)  alloc((size_t)2 * 8 * 16384 * 2); // 2 layers x 8-slot ring
  float*    Hf    = (float*)alloc((size_t)2 * 8192 * 4);
  u16*      Wc    = (u16*)  alloc((size_t)3145728 * 2);       // [w1|w2|ww|pw] bf16
  float*    sums  = (float*)alloc(16 * 4);
  unsigned* flags = (unsigned*)alloc((size_t)FLAGS_TOTAL * 4);
  unsigned* poi   = (unsigned*)alloc(256);

  u16* WcW1 = Wc;
  u16* WcW2 = Wc + 1048576;
  u16* WcWW = Wc + 2097152;
  u16* WcPW = Wc + 2621440;

  k_conv<<<2048, 256, 0, stream>>>((const float*)d_in[0], (const float*)d_in[1],
                                   (const float*)d_in[4], (const float*)d_in[8],
                                   (const float*)d_in[10],
                                   Xb, Wc, Hf, Hb, sums, flags, poi);

  for (int loop = 0; loop < 3; ++loop) {
    k_gemm<0><<<256, 512, 0, stream>>>(Xb, WcW1, b1, r1w, nullptr, nullptr, T1, nullptr, 1024);
    k_gemm<1><<<256, 512, 0, stream>>>(T1, WcW2, b2, r2w, Xb, rw, XrefB, nullptr, 1024);
    k_rec<<<128, 256, 0, stream>>>(wih0, whh0, bih0, bhh0, wih1, whh1, bih1, bhh1,
                                   XrefB, gi0r, gi1r, Hb, Hf, Xb,
                                   (loop == 2) ? out : nullptr, flags, poi, loop);
    if (loop < 2)
      k_gemm<2><<<256, 512, 0, stream>>>(Xb, WcPW, pb, nullptr, nullptr, nullptr, nullptr, sums, 512);
    else
      k_gemm<2><<<256, 512, 0, stream>>>(Xb, WcWW, wb, nullptr, nullptr, nullptr, nullptr, sums + 8, 512);
  }
  k_phi<<<1, 64, 0, stream>>>(sums, psc, pbi, out);
}